// Round 6
// baseline (201.621 us; speedup 1.0000x reference)
//
#include <hip/hip_runtime.h>
#include <stdint.h>

// EdgeNetwork, round 11: SPLIT ranking from msg to partition the 55us wall.
// r10 post-mortem: order[] scatter added 18MB write-allocate (WRITE 40.6->58.5)
// and GPW=1 quadrupled kern-prologue cost -> regression; reverted to r8 base.
// Key fact: r3's msg had NO atomic and was also ~55us; six variants since all
// land 55-65us with atomic+compute confounded. This round separates them:
//   rank_kernel: 1 lane/edge, pair -> atomicAdd -> coalesced slot[e] store.
//                Its duration IS the isolated atomic cost.
//   msg_mfma:    r8 structure, atomic-free (reads slot[e] instead).
//                Its duration IS the isolated compute-path cost.
// CAP 64->56 so ws fits under the proven-available size (msgs 35.8MB,
// needed ~40MB < r8's passing 42.5MB). P(deg>=56)~4e-5/atom -> ~1 oflow
// atom expected, handled by the existing oflow path.
// History: r1 630 -> r2 CSR 333 -> r3 MFMA 190 -> r4 binning 150 -> r5 148.8
// -> r6 147.3 (msg 61) -> r7 136.5 (msg 55.5) -> r8 133.0 (msg 57.7, BEST)
// -> r9 138 (sched_barrier defeated) -> r10 154 (order-scatter regression).

constexpr int DIM  = 16;
constexpr int CAP  = 56;     // slots per atom; P(deg>=56) ~ 4e-5 at Poisson(32)
constexpr int CSTR = 16;     // counts stride (ints) = one 64B line per atom
constexpr int OFLOW_CAP = 65536;
constexpr int GPW  = 4;      // 16-edge groups per wave, fully unrolled

using frag_ab = __attribute__((ext_vector_type(8))) short;   // 8 bf16
using frag_cd = __attribute__((ext_vector_type(4))) float;   // 4 f32
union ABPack { frag_ab f; uint32_t u[4]; };

__device__ __forceinline__ uint32_t pack_bf16_2(float lo, float hi) {
    // one v_perm_b32: truncate-to-bf16 pair, lo in low 16 bits
    return __builtin_amdgcn_perm(__float_as_uint(hi), __float_as_uint(lo), 0x07060302u);
}

// ---- rank kernel: PURE atomic pass at max TLP. slot[e] coalesced 4B store.
__global__ __launch_bounds__(256) void rank_kernel(
    const int* __restrict__ pair, int* __restrict__ counts,
    int* __restrict__ oflow_cnt, int* __restrict__ oflow,
    int* __restrict__ slot_arr, int n_edges)
{
    int e = blockIdx.x * blockDim.x + threadIdx.x;
    if (e >= n_edges) return;
    int2 pr = ((const int2*)pair)[e];
    int r = atomicAdd(&counts[pr.x * CSTR], 1);
    int slot;
    if (r < CAP) {
        slot = pr.x * CAP + r;
    } else {
        slot = -1;
        int oi = atomicAdd(oflow_cnt, 1);
        if (oi < OFLOW_CAP) oflow[oi] = e;
    }
    slot_arr[e] = slot;
}

// ---- msg kernel: r8 structure, ATOMIC-FREE (slot read from rank pass)
__global__ __launch_bounds__(256, 3) void msg_mfma_kernel(
    const float* __restrict__ atom, const float* __restrict__ bond,
    const int*   __restrict__ pair, const float* __restrict__ kern,
    const float* __restrict__ bias, const int* __restrict__ slot_arr,
    uint16_t* __restrict__ msgs, int n_edges, int n_groups)
{
    const int wave = (int)((blockIdx.x * blockDim.x + threadIdx.x) >> 6);
    const int lane = threadIdx.x & 63;
    const int g0 = wave * GPW;
    if (g0 >= n_groups) return;

    const int col  = lane & 15;        // A(W): output row i | B(Z): edge e | D: col e
    const int quad = lane >> 4;        // 0..3
    const int hb   = quad >> 1;        // k parity within chunk (0/1, fixed per lane)
    const int j0   = (quad & 1) * 8;   // neigh sub-range (for W/bias frag layout)

    // P1: pair + slot loads (quad0 lanes only)
    int  ec_[GPW];
    int  sl_[GPW];
    int  srcq_[GPW];
#pragma unroll
    for (int u = 0; u < GPW; ++u) {
        const int e = ((g0 + u) << 4) + col;
        ec_[u] = min(e, n_edges - 1);
        sl_[u] = -1;
        srcq_[u] = 0;
        if (quad == 0) {
            int2 pr = ((const int2*)pair)[ec_[u]];
            srcq_[u] = pr.y;
            if (e < n_edges) sl_[u] = slot_arr[ec_[u]];
        }
    }

    // W fragments (L1-hot broadcast; overlaps P1 latency)
    frag_ab wfrag[8];
#pragma unroll
    for (int c = 0; c < 8; ++c) {
        const float* wp = kern + (2 * c + hb) * 256 + col * 16 + j0;
        float4 w0 = *(const float4*)wp;
        float4 w1 = *(const float4*)(wp + 4);
        ABPack p;
        p.u[0] = pack_bf16_2(w0.x, w0.y);
        p.u[1] = pack_bf16_2(w0.z, w0.w);
        p.u[2] = pack_bf16_2(w1.x, w1.y);
        p.u[3] = pack_bf16_2(w1.z, w1.w);
        wfrag[c] = p.f;
    }
    frag_ab bias_a;
    {
        ABPack p; p.u[0] = p.u[1] = p.u[2] = p.u[3] = 0;
        if (hb == 0) {
            const float* bp2 = bias + col * 16 + j0;
            float4 w0 = *(const float4*)bp2;
            float4 w1 = *(const float4*)(bp2 + 4);
            p.u[0] = pack_bf16_2(w0.x, w0.y);
            p.u[1] = pack_bf16_2(w0.z, w0.w);
            p.u[2] = pack_bf16_2(w1.x, w1.y);
            p.u[3] = pack_bf16_2(w1.z, w1.w);
        }
        bias_a = p.f;
    }

    // src broadcast
    int src_[GPW];
#pragma unroll
    for (int u = 0; u < GPW; ++u) src_[u] = __shfl(srcq_[u], col, 64);

    // P2: dedup gathers. atom: chunk cq=[0,2,1,3][quad] of src row (one xor32
    // restores both halves). bond: chunk `quad` -> 1KB contiguous per group.
    const int cq = ((quad & 1) << 1) | (quad >> 1);
    float4 am_[GPW], bm_[GPW];
#pragma unroll
    for (int u = 0; u < GPW; ++u) {
        am_[u] = *(const float4*)(atom + (size_t)src_[u] * DIM + cq * 4);
        bm_[u] = *(const float4*)(bond + (size_t)ec_[u] * DIM + quad * 4);
    }

    // P4: per group: redistribute + pack + MFMA + store
#pragma unroll
    for (int u = 0; u < GPW; ++u) {
        // atom exchange: xor32 swaps chunk pairs (0<->1, 2<->3)
        float4 am = am_[u];
        float4 ao;
        ao.x = __shfl_xor(am.x, 32); ao.y = __shfl_xor(am.y, 32);
        ao.z = __shfl_xor(am.z, 32); ao.w = __shfl_xor(am.w, 32);
        float nb[8];
        nb[0] = quad < 2 ? am.x : ao.x;  nb[1] = quad < 2 ? am.y : ao.y;
        nb[2] = quad < 2 ? am.z : ao.z;  nb[3] = quad < 2 ? am.w : ao.w;
        nb[4] = quad < 2 ? ao.x : am.x;  nb[5] = quad < 2 ? ao.y : am.y;
        nb[6] = quad < 2 ? ao.z : am.z;  nb[7] = quad < 2 ? ao.w : am.w;

        // bond butterfly: stage1 xor16 pairs chunks within a half
        float4 bm = bm_[u];
        float4 bo;
        bo.x = __shfl_xor(bm.x, 16); bo.y = __shfl_xor(bm.y, 16);
        bo.z = __shfl_xor(bm.z, 16); bo.w = __shfl_xor(bm.w, 16);
        float4 cA, cB;   // even / odd chunk of this lane's half
        cA.x = (quad & 1) ? bo.x : bm.x; cA.y = (quad & 1) ? bo.y : bm.y;
        cA.z = (quad & 1) ? bo.z : bm.z; cA.w = (quad & 1) ? bo.w : bm.w;
        cB.x = (quad & 1) ? bm.x : bo.x; cB.y = (quad & 1) ? bm.y : bo.y;
        cB.z = (quad & 1) ? bm.z : bo.z; cB.w = (quad & 1) ? bm.w : bo.w;
        float s0 = hb ? cA.y : cA.x,  s1 = hb ? cA.w : cA.z;
        float s2 = hb ? cB.y : cB.x,  s3 = hb ? cB.w : cB.z;
        float g0v = hb ? cA.x : cA.y, g1v = hb ? cA.z : cA.w;
        float g2v = hb ? cB.x : cB.y, g3v = hb ? cB.z : cB.w;
        float t0 = __shfl_xor(g0v, 32), t1 = __shfl_xor(g1v, 32);
        float t2 = __shfl_xor(g2v, 32), t3 = __shfl_xor(g3v, 32);
        float bks[8];
        bks[0] = quad < 2 ? s0 : t0;  bks[1] = quad < 2 ? s1 : t1;
        bks[2] = quad < 2 ? s2 : t2;  bks[3] = quad < 2 ? s3 : t3;
        bks[4] = quad < 2 ? t0 : s0;  bks[5] = quad < 2 ? t1 : s1;
        bks[6] = quad < 2 ? t2 : s2;  bks[7] = quad < 2 ? t3 : s3;

        // dual accumulators (even/odd k-chunk) to halve serial MFMA latency
        frag_cd acc0 = {0.f, 0.f, 0.f, 0.f};
        frag_cd acc1 = {0.f, 0.f, 0.f, 0.f};
#pragma unroll
        for (int c = 0; c < 8; ++c) {
            const float bk = bks[c];
            ABPack z;
            z.u[0] = pack_bf16_2(bk * nb[0], bk * nb[1]);
            z.u[1] = pack_bf16_2(bk * nb[2], bk * nb[3]);
            z.u[2] = pack_bf16_2(bk * nb[4], bk * nb[5]);
            z.u[3] = pack_bf16_2(bk * nb[6], bk * nb[7]);
            if (c & 1)
                acc1 = __builtin_amdgcn_mfma_f32_16x16x32_bf16(wfrag[c], z.f, acc1, 0, 0, 0);
            else
                acc0 = __builtin_amdgcn_mfma_f32_16x16x32_bf16(wfrag[c], z.f, acc0, 0, 0, 0);
        }
        { // bias chunk (k<16 half only)
            ABPack z; z.u[0] = z.u[1] = z.u[2] = z.u[3] = 0;
            if (hb == 0) {
                z.u[0] = pack_bf16_2(nb[0], nb[1]);
                z.u[1] = pack_bf16_2(nb[2], nb[3]);
                z.u[2] = pack_bf16_2(nb[4], nb[5]);
                z.u[3] = pack_bf16_2(nb[6], nb[7]);
            }
            acc1 = __builtin_amdgcn_mfma_f32_16x16x32_bf16(bias_a, z.f, acc1, 0, 0, 0);
        }
        frag_cd acc = acc0 + acc1;

        // slot broadcast from quad0 lane `col`; xor16-merge quad pairs so
        // quads 0,2 issue one 16B store each.
        const int s = __shfl(sl_[u], col, 64);
        uint2 pkd;
        pkd.x = pack_bf16_2(acc[0], acc[1]);
        pkd.y = pack_bf16_2(acc[2], acc[3]);
        uint32_t qx = __shfl_xor(pkd.x, 16);
        uint32_t qy = __shfl_xor(pkd.y, 16);
        if (s >= 0 && (quad & 1) == 0) {
            uint4 w4 = make_uint4(pkd.x, pkd.y, qx, qy);
            *(uint4*)(msgs + (size_t)s * DIM + (quad & 2) * 4) = w4;
        }
    }
}

// ---- reduce: 32 threads/atom over fixed-stride bf16 slots, atomic-free
__global__ __launch_bounds__(256) void reduce_kernel(
    const uint16_t* __restrict__ msgs, const int* __restrict__ counts,
    float* __restrict__ out, int n_atoms)
{
    int t = blockIdx.x * blockDim.x + threadIdx.x;
    int a = t >> 5;
    if (a >= n_atoms) return;
    int c = t & 3;          // 4-col chunk (8B)
    int q = (t >> 2) & 7;   // 8-way split of the message list

    int cnt = min(counts[a * CSTR], CAP);
    const uint32_t* base = (const uint32_t*)(msgs + (size_t)a * CAP * DIM);

    float4 acc = make_float4(0.f, 0.f, 0.f, 0.f);
    for (int j = q; j < cnt; j += 8) {
        uint2 v = *(const uint2*)(base + j * 8 + c * 2);     // 4 bf16 = 8 B
        acc.x += __uint_as_float(v.x << 16);
        acc.y += __uint_as_float(v.x & 0xFFFF0000u);
        acc.z += __uint_as_float(v.y << 16);
        acc.w += __uint_as_float(v.y & 0xFFFF0000u);
    }
    // combine the 8-way q split (lane bits 2..4)
    acc.x += __shfl_xor(acc.x, 4);  acc.y += __shfl_xor(acc.y, 4);
    acc.z += __shfl_xor(acc.z, 4);  acc.w += __shfl_xor(acc.w, 4);
    acc.x += __shfl_xor(acc.x, 8);  acc.y += __shfl_xor(acc.y, 8);
    acc.z += __shfl_xor(acc.z, 8);  acc.w += __shfl_xor(acc.w, 8);
    acc.x += __shfl_xor(acc.x, 16); acc.y += __shfl_xor(acc.y, 16);
    acc.z += __shfl_xor(acc.z, 16); acc.w += __shfl_xor(acc.w, 16);
    if (q == 0)
        ((float4*)(out + (size_t)a * DIM))[c] = acc;
}

// ---- overflow fix-up (normally ~0-3 edges): scalar f32 + atomicAdd, AFTER reduce
__global__ __launch_bounds__(256) void oflow_kernel(
    const float* __restrict__ atom, const float* __restrict__ bond,
    const int*   __restrict__ pair, const float* __restrict__ kern,
    const float* __restrict__ bias,
    const int* __restrict__ oflow_cnt, const int* __restrict__ oflow,
    float* __restrict__ out, int n_edges)
{
    int n = min(*oflow_cnt, OFLOW_CAP);
    for (int i = blockIdx.x * blockDim.x + threadIdx.x; i < n;
         i += gridDim.x * blockDim.x) {
        int e   = oflow[i];
        int dst = pair[2 * e + 0];
        int src = pair[2 * e + 1];
        float neigh[DIM], bnd[DIM], acc[DIM];
        for (int q = 0; q < DIM; ++q) neigh[q] = atom[(size_t)src * DIM + q];
        for (int q = 0; q < DIM; ++q) bnd[q]   = bond[(size_t)e * DIM + q];
#pragma unroll
        for (int ii = 0; ii < DIM; ++ii) {
            float d = 0.f;
#pragma unroll
            for (int j = 0; j < DIM; ++j) d = fmaf(bias[ii * DIM + j], neigh[j], d);
            acc[ii] = d;
        }
#pragma unroll 1
        for (int k = 0; k < DIM; ++k) {
            const float bk = bnd[k];
            const float* Kr = kern + k * (DIM * DIM);
#pragma unroll
            for (int ii = 0; ii < DIM; ++ii) {
                float d = 0.f;
#pragma unroll
                for (int j = 0; j < DIM; ++j) d = fmaf(Kr[ii * DIM + j], neigh[j], d);
                acc[ii] = fmaf(bk, d, acc[ii]);
            }
        }
#pragma unroll
        for (int ii = 0; ii < DIM; ++ii) atomicAdd(&out[(size_t)dst * DIM + ii], acc[ii]);
    }
}

// ---- safety fallback if ws too small (round-1 structure)
__global__ __launch_bounds__(256) void edge_atomic_kernel(
    const float* __restrict__ atom, const float* __restrict__ bond,
    const int*   __restrict__ pair, const float* __restrict__ kern,
    const float* __restrict__ bias, float* __restrict__ out, int n_edges)
{
    int e = blockIdx.x * blockDim.x + threadIdx.x;
    if (e >= n_edges) return;
    int dst = pair[2 * e + 0];
    int src = pair[2 * e + 1];
    float neigh[DIM], bnd[DIM], acc[DIM];
    for (int q = 0; q < DIM; ++q) neigh[q] = atom[(size_t)src * DIM + q];
    for (int q = 0; q < DIM; ++q) bnd[q]   = bond[(size_t)e * DIM + q];
#pragma unroll
    for (int i = 0; i < DIM; ++i) {
        float d = 0.f;
#pragma unroll
        for (int j = 0; j < DIM; ++j) d = fmaf(bias[i * DIM + j], neigh[j], d);
        acc[i] = d;
    }
#pragma unroll 1
    for (int k = 0; k < DIM; ++k) {
        const float bk = bnd[k];
        const float* Kr = kern + k * (DIM * DIM);
#pragma unroll
        for (int i = 0; i < DIM; ++i) {
            float d = 0.f;
#pragma unroll
            for (int j = 0; j < DIM; ++j) d = fmaf(Kr[i * DIM + j], neigh[j], d);
            acc[i] = fmaf(bk, d, acc[i]);
        }
    }
#pragma unroll
    for (int i = 0; i < DIM; ++i) atomicAdd(&out[(size_t)dst * DIM + i], acc[i]);
}

extern "C" void kernel_launch(void* const* d_in, const int* in_sizes, int n_in,
                              void* d_out, int out_size, void* d_ws, size_t ws_size,
                              hipStream_t stream)
{
    const float* atom = (const float*)d_in[0];   // (20000,16) f32
    const float* bond = (const float*)d_in[1];   // (640000,16) f32
    const int*   pair = (const int*)d_in[2];     // (640000,2) i32 [dst, src]
    const float* kern = (const float*)d_in[3];   // (16,256) f32
    const float* bias = (const float*)d_in[4];   // (256,) f32
    float*       out  = (float*)d_out;           // (20000,16) f32

    const int n_edges = in_sizes[1] / DIM;       // 640000
    const int n_atoms = in_sizes[0] / DIM;       // 20000

    // ws: counts[n_atoms*CSTR] | oflow_cnt[1] | oflow[OFLOW_CAP] | 64B |
    //     slot[n_edges] | 64B | msgs bf16[n_atoms*CAP*DIM]
    size_t counts_off = 0;
    size_t ocnt_off   = counts_off + (size_t)n_atoms * CSTR * sizeof(int);
    size_t oflow_off  = ocnt_off + sizeof(int);
    size_t slot_off   = (oflow_off + (size_t)OFLOW_CAP * sizeof(int) + 63) & ~(size_t)63;
    size_t msgs_off   = (slot_off + (size_t)n_edges * sizeof(int) + 63) & ~(size_t)63;
    size_t needed     = msgs_off + (size_t)n_atoms * CAP * DIM * sizeof(uint16_t);

    const int threads = 256;

    if (ws_size >= needed) {
        int*      counts    = (int*)((char*)d_ws + counts_off);
        int*      oflow_cnt = (int*)((char*)d_ws + ocnt_off);
        int*      oflow     = (int*)((char*)d_ws + oflow_off);
        int*      slot_arr  = (int*)((char*)d_ws + slot_off);
        uint16_t* msgs      = (uint16_t*)((char*)d_ws + msgs_off);

        // zero counts (padded) + oflow counter in one contiguous memset
        hipMemsetAsync(counts, 0, (size_t)n_atoms * CSTR * sizeof(int) + sizeof(int),
                       stream);

        // pass 1: pure ranking (isolated atomic cost)
        rank_kernel<<<(n_edges + threads - 1) / threads, threads, 0, stream>>>(
            pair, counts, oflow_cnt, oflow, slot_arr, n_edges);

        // pass 2: atomic-free msg compute (isolated compute-path cost)
        const int n_groups = (n_edges + 15) / 16;
        const int waves    = (n_groups + GPW - 1) / GPW;
        const int mblocks  = (waves * 64 + threads - 1) / threads;
        msg_mfma_kernel<<<mblocks, threads, 0, stream>>>(
            atom, bond, pair, kern, bias, slot_arr, msgs, n_edges, n_groups);

        // pass 3: reduce
        const int rthreads = n_atoms * 32;
        reduce_kernel<<<(rthreads + threads - 1) / threads, threads, 0, stream>>>(
            msgs, counts, out, n_atoms);

        // pass 4: overflow fix-up (rarely does work)
        oflow_kernel<<<8, threads, 0, stream>>>(
            atom, bond, pair, kern, bias, oflow_cnt, oflow, out, n_edges);
    } else {
        hipMemsetAsync(out, 0, (size_t)out_size * sizeof(float), stream);
        edge_atomic_kernel<<<(n_edges + threads - 1) / threads, threads, 0, stream>>>(
            atom, bond, pair, kern, bias, out, n_edges);
    }
}

// Round 7
// 133.474 us; speedup vs baseline: 1.5106x; 1.5106x over previous
//
#include <hip/hip_runtime.h>
#include <stdint.h>

// EdgeNetwork, round 12: KILL the trailing kernels.
// r11's split surfaced the real structure: oflow_kernel (8 blocks, zero work:
// VALU 0.02%, 50KB fetch) costs 66.7us flat -- and has been hiding below the
// top-5 cutoff since r4 (r8's 133 = msg 57.7 + oflow ~66 + reduce ~15 + memset).
// Five rounds optimized msg while a do-nothing dispatch burned 45% of budget.
// Fix: revert msg to r8's inline-atomic structure (proven 57.7us) and fold the
// overflow fixup INTO msg: when r>=CAP the wave already holds the message ->
// 16 f32 atomicAdds into a zeroed oflow_acc[n_atoms][16] side buffer (~0-3
// edges total). reduce adds oflow_acc[a] into its sum. Dispatches: memset,
// msg, reduce. rank_kernel + oflow_kernel deleted.
// History: r1 630 -> r2 CSR 333 -> r3 MFMA 190 -> r4 binning 150 -> r5 148.8
// -> r6 147.3 -> r7 136.5 -> r8 133.0 (BEST) -> r9 138 -> r10 154 -> r11 202
// (split isolated oflow=66us dead time, msg/compute exonerated).

constexpr int DIM  = 16;
constexpr int CAP  = 56;     // slots per atom; P(deg>=56) ~ 4e-5 at Poisson(32)
constexpr int CSTR = 16;     // counts stride (ints) = one 64B line per atom
constexpr int GPW  = 4;      // 16-edge groups per wave, fully unrolled

using frag_ab = __attribute__((ext_vector_type(8))) short;   // 8 bf16
using frag_cd = __attribute__((ext_vector_type(4))) float;   // 4 f32
union ABPack { frag_ab f; uint32_t u[4]; };

__device__ __forceinline__ uint32_t pack_bf16_2(float lo, float hi) {
    // one v_perm_b32: truncate-to-bf16 pair, lo in low 16 bits
    return __builtin_amdgcn_perm(__float_as_uint(hi), __float_as_uint(lo), 0x07060302u);
}

// ---- msg kernel: r8 structure + inline overflow accumulation
__global__ __launch_bounds__(256, 3) void msg_mfma_kernel(
    const float* __restrict__ atom, const float* __restrict__ bond,
    const int*   __restrict__ pair, const float* __restrict__ kern,
    const float* __restrict__ bias,
    int* __restrict__ counts, float* __restrict__ oflow_acc,
    uint16_t* __restrict__ msgs, int n_edges, int n_groups)
{
    const int wave = (int)((blockIdx.x * blockDim.x + threadIdx.x) >> 6);
    const int lane = threadIdx.x & 63;
    const int g0 = wave * GPW;
    if (g0 >= n_groups) return;

    const int col  = lane & 15;        // A(W): output row i | B(Z): edge e | D: col e
    const int quad = lane >> 4;        // 0..3
    const int hb   = quad >> 1;        // k parity within chunk (0/1, fixed per lane)
    const int j0   = (quad & 1) * 8;   // neigh sub-range (for W/bias frag layout)

    // P1: pair loads (quad0 lanes only)
    int  ec_[GPW];
    int2 pr_[GPW];
#pragma unroll
    for (int u = 0; u < GPW; ++u) {
        const int e = ((g0 + u) << 4) + col;
        ec_[u] = min(e, n_edges - 1);
        pr_[u] = make_int2(0, 0);
        if (quad == 0) pr_[u] = ((const int2*)pair)[ec_[u]];
    }

    // W fragments (L1-hot broadcast; overlaps P1 latency)
    frag_ab wfrag[8];
#pragma unroll
    for (int c = 0; c < 8; ++c) {
        const float* wp = kern + (2 * c + hb) * 256 + col * 16 + j0;
        float4 w0 = *(const float4*)wp;
        float4 w1 = *(const float4*)(wp + 4);
        ABPack p;
        p.u[0] = pack_bf16_2(w0.x, w0.y);
        p.u[1] = pack_bf16_2(w0.z, w0.w);
        p.u[2] = pack_bf16_2(w1.x, w1.y);
        p.u[3] = pack_bf16_2(w1.z, w1.w);
        wfrag[c] = p.f;
    }
    frag_ab bias_a;
    {
        ABPack p; p.u[0] = p.u[1] = p.u[2] = p.u[3] = 0;
        if (hb == 0) {
            const float* bp2 = bias + col * 16 + j0;
            float4 w0 = *(const float4*)bp2;
            float4 w1 = *(const float4*)(bp2 + 4);
            p.u[0] = pack_bf16_2(w0.x, w0.y);
            p.u[1] = pack_bf16_2(w0.z, w0.w);
            p.u[2] = pack_bf16_2(w1.x, w1.y);
            p.u[3] = pack_bf16_2(w1.z, w1.w);
        }
        bias_a = p.f;
    }

    // src broadcast
    int src_[GPW];
#pragma unroll
    for (int u = 0; u < GPW; ++u) src_[u] = __shfl(pr_[u].y, col, 64);

    // P2: dedup gathers. atom: chunk cq=[0,2,1,3][quad] of src row (one xor32
    // restores both halves). bond: chunk `quad` -> 1KB contiguous per group.
    const int cq = ((quad & 1) << 1) | (quad >> 1);
    float4 am_[GPW], bm_[GPW];
#pragma unroll
    for (int u = 0; u < GPW; ++u) {
        am_[u] = *(const float4*)(atom + (size_t)src_[u] * DIM + cq * 4);
        bm_[u] = *(const float4*)(bond + (size_t)ec_[u] * DIM + quad * 4);
    }

    // P3: rank atomics (after gathers; consumed only at store time)
    int r_[GPW];
#pragma unroll
    for (int u = 0; u < GPW; ++u) {
        r_[u] = CAP;
        const int e = ((g0 + u) << 4) + col;
        if (quad == 0 && e < n_edges)
            r_[u] = atomicAdd(&counts[pr_[u].x * CSTR], 1);
    }

    // P4: per group: redistribute + pack + MFMA + store
#pragma unroll
    for (int u = 0; u < GPW; ++u) {
        // atom exchange: xor32 swaps chunk pairs (0<->1, 2<->3)
        float4 am = am_[u];
        float4 ao;
        ao.x = __shfl_xor(am.x, 32); ao.y = __shfl_xor(am.y, 32);
        ao.z = __shfl_xor(am.z, 32); ao.w = __shfl_xor(am.w, 32);
        float nb[8];
        nb[0] = quad < 2 ? am.x : ao.x;  nb[1] = quad < 2 ? am.y : ao.y;
        nb[2] = quad < 2 ? am.z : ao.z;  nb[3] = quad < 2 ? am.w : ao.w;
        nb[4] = quad < 2 ? ao.x : am.x;  nb[5] = quad < 2 ? ao.y : am.y;
        nb[6] = quad < 2 ? ao.z : am.z;  nb[7] = quad < 2 ? ao.w : am.w;

        // bond butterfly: stage1 xor16 pairs chunks within a half
        float4 bm = bm_[u];
        float4 bo;
        bo.x = __shfl_xor(bm.x, 16); bo.y = __shfl_xor(bm.y, 16);
        bo.z = __shfl_xor(bm.z, 16); bo.w = __shfl_xor(bm.w, 16);
        float4 cA, cB;   // even / odd chunk of this lane's half
        cA.x = (quad & 1) ? bo.x : bm.x; cA.y = (quad & 1) ? bo.y : bm.y;
        cA.z = (quad & 1) ? bo.z : bm.z; cA.w = (quad & 1) ? bo.w : bm.w;
        cB.x = (quad & 1) ? bm.x : bo.x; cB.y = (quad & 1) ? bm.y : bo.y;
        cB.z = (quad & 1) ? bm.z : bo.z; cB.w = (quad & 1) ? bm.w : bo.w;
        float s0 = hb ? cA.y : cA.x,  s1 = hb ? cA.w : cA.z;
        float s2 = hb ? cB.y : cB.x,  s3 = hb ? cB.w : cB.z;
        float g0v = hb ? cA.x : cA.y, g1v = hb ? cA.z : cA.w;
        float g2v = hb ? cB.x : cB.y, g3v = hb ? cB.z : cB.w;
        float t0 = __shfl_xor(g0v, 32), t1 = __shfl_xor(g1v, 32);
        float t2 = __shfl_xor(g2v, 32), t3 = __shfl_xor(g3v, 32);
        float bks[8];
        bks[0] = quad < 2 ? s0 : t0;  bks[1] = quad < 2 ? s1 : t1;
        bks[2] = quad < 2 ? s2 : t2;  bks[3] = quad < 2 ? s3 : t3;
        bks[4] = quad < 2 ? t0 : s0;  bks[5] = quad < 2 ? t1 : s1;
        bks[6] = quad < 2 ? t2 : s2;  bks[7] = quad < 2 ? t3 : s3;

        // dual accumulators (even/odd k-chunk) to halve serial MFMA latency
        frag_cd acc0 = {0.f, 0.f, 0.f, 0.f};
        frag_cd acc1 = {0.f, 0.f, 0.f, 0.f};
#pragma unroll
        for (int c = 0; c < 8; ++c) {
            const float bk = bks[c];
            ABPack z;
            z.u[0] = pack_bf16_2(bk * nb[0], bk * nb[1]);
            z.u[1] = pack_bf16_2(bk * nb[2], bk * nb[3]);
            z.u[2] = pack_bf16_2(bk * nb[4], bk * nb[5]);
            z.u[3] = pack_bf16_2(bk * nb[6], bk * nb[7]);
            if (c & 1)
                acc1 = __builtin_amdgcn_mfma_f32_16x16x32_bf16(wfrag[c], z.f, acc1, 0, 0, 0);
            else
                acc0 = __builtin_amdgcn_mfma_f32_16x16x32_bf16(wfrag[c], z.f, acc0, 0, 0, 0);
        }
        { // bias chunk (k<16 half only)
            ABPack z; z.u[0] = z.u[1] = z.u[2] = z.u[3] = 0;
            if (hb == 0) {
                z.u[0] = pack_bf16_2(nb[0], nb[1]);
                z.u[1] = pack_bf16_2(nb[2], nb[3]);
                z.u[2] = pack_bf16_2(nb[4], nb[5]);
                z.u[3] = pack_bf16_2(nb[6], nb[7]);
            }
            acc1 = __builtin_amdgcn_mfma_f32_16x16x32_bf16(bias_a, z.f, acc1, 0, 0, 0);
        }
        frag_cd acc = acc0 + acc1;

        // slot resolve + broadcasts (unconditional: shfl sources stay active)
        int slot = -1;
        const int e = ((g0 + u) << 4) + col;
        if (quad == 0 && e < n_edges && r_[u] < CAP)
            slot = pr_[u].x * CAP + r_[u];
        const int s    = __shfl(slot, col, 64);      // from quad0 lane `col`
        const int dstb = __shfl(pr_[u].x, col, 64);  // dst atom of edge `col`

        // D^T: lane (quad,col) holds msgs[e=col][i=quad*4 .. +3].
        // xor16-merge quad pairs -> quads 0,2 issue one 16B store each.
        uint2 pkd;
        pkd.x = pack_bf16_2(acc[0], acc[1]);
        pkd.y = pack_bf16_2(acc[2], acc[3]);
        uint32_t qx = __shfl_xor(pkd.x, 16);
        uint32_t qy = __shfl_xor(pkd.y, 16);
        if (e < n_edges) {
            if (s >= 0) {
                if ((quad & 1) == 0) {
                    uint4 w4 = make_uint4(pkd.x, pkd.y, qx, qy);
                    *(uint4*)(msgs + (size_t)s * DIM + (quad & 2) * 4) = w4;
                }
            } else {
                // overflow (rare, ~0-3 edges/launch): accumulate f32 directly
                atomicAdd(&oflow_acc[(size_t)dstb * DIM + quad * 4 + 0], acc[0]);
                atomicAdd(&oflow_acc[(size_t)dstb * DIM + quad * 4 + 1], acc[1]);
                atomicAdd(&oflow_acc[(size_t)dstb * DIM + quad * 4 + 2], acc[2]);
                atomicAdd(&oflow_acc[(size_t)dstb * DIM + quad * 4 + 3], acc[3]);
            }
        }
    }
}

// ---- reduce: 32 threads/atom over fixed-stride bf16 slots + oflow_acc
__global__ __launch_bounds__(256) void reduce_kernel(
    const uint16_t* __restrict__ msgs, const int* __restrict__ counts,
    const float* __restrict__ oflow_acc, float* __restrict__ out, int n_atoms)
{
    int t = blockIdx.x * blockDim.x + threadIdx.x;
    int a = t >> 5;
    if (a >= n_atoms) return;
    int c = t & 3;          // 4-col chunk (8B)
    int q = (t >> 2) & 7;   // 8-way split of the message list

    int cnt = min(counts[a * CSTR], CAP);
    const uint32_t* base = (const uint32_t*)(msgs + (size_t)a * CAP * DIM);

    float4 acc = make_float4(0.f, 0.f, 0.f, 0.f);
    for (int j = q; j < cnt; j += 8) {
        uint2 v = *(const uint2*)(base + j * 8 + c * 2);     // 4 bf16 = 8 B
        acc.x += __uint_as_float(v.x << 16);
        acc.y += __uint_as_float(v.x & 0xFFFF0000u);
        acc.z += __uint_as_float(v.y << 16);
        acc.w += __uint_as_float(v.y & 0xFFFF0000u);
    }
    // combine the 8-way q split (lane bits 2..4)
    acc.x += __shfl_xor(acc.x, 4);  acc.y += __shfl_xor(acc.y, 4);
    acc.z += __shfl_xor(acc.z, 4);  acc.w += __shfl_xor(acc.w, 4);
    acc.x += __shfl_xor(acc.x, 8);  acc.y += __shfl_xor(acc.y, 8);
    acc.z += __shfl_xor(acc.z, 8);  acc.w += __shfl_xor(acc.w, 8);
    acc.x += __shfl_xor(acc.x, 16); acc.y += __shfl_xor(acc.y, 16);
    acc.z += __shfl_xor(acc.z, 16); acc.w += __shfl_xor(acc.w, 16);
    if (q == 0) {
        float4 oa = *(const float4*)(oflow_acc + (size_t)a * DIM + c * 4);
        acc.x += oa.x; acc.y += oa.y; acc.z += oa.z; acc.w += oa.w;
        ((float4*)(out + (size_t)a * DIM))[c] = acc;
    }
}

// ---- safety fallback if ws too small (round-1 structure)
__global__ __launch_bounds__(256) void edge_atomic_kernel(
    const float* __restrict__ atom, const float* __restrict__ bond,
    const int*   __restrict__ pair, const float* __restrict__ kern,
    const float* __restrict__ bias, float* __restrict__ out, int n_edges)
{
    int e = blockIdx.x * blockDim.x + threadIdx.x;
    if (e >= n_edges) return;
    int dst = pair[2 * e + 0];
    int src = pair[2 * e + 1];
    float neigh[DIM], bnd[DIM], acc[DIM];
    for (int q = 0; q < DIM; ++q) neigh[q] = atom[(size_t)src * DIM + q];
    for (int q = 0; q < DIM; ++q) bnd[q]   = bond[(size_t)e * DIM + q];
#pragma unroll
    for (int i = 0; i < DIM; ++i) {
        float d = 0.f;
#pragma unroll
        for (int j = 0; j < DIM; ++j) d = fmaf(bias[i * DIM + j], neigh[j], d);
        acc[i] = d;
    }
#pragma unroll 1
    for (int k = 0; k < DIM; ++k) {
        const float bk = bnd[k];
        const float* Kr = kern + k * (DIM * DIM);
#pragma unroll
        for (int i = 0; i < DIM; ++i) {
            float d = 0.f;
#pragma unroll
            for (int j = 0; j < DIM; ++j) d = fmaf(Kr[i * DIM + j], neigh[j], d);
            acc[i] = fmaf(bk, d, acc[i]);
        }
    }
#pragma unroll
    for (int i = 0; i < DIM; ++i) atomicAdd(&out[(size_t)dst * DIM + i], acc[i]);
}

extern "C" void kernel_launch(void* const* d_in, const int* in_sizes, int n_in,
                              void* d_out, int out_size, void* d_ws, size_t ws_size,
                              hipStream_t stream)
{
    const float* atom = (const float*)d_in[0];   // (20000,16) f32
    const float* bond = (const float*)d_in[1];   // (640000,16) f32
    const int*   pair = (const int*)d_in[2];     // (640000,2) i32 [dst, src]
    const float* kern = (const float*)d_in[3];   // (16,256) f32
    const float* bias = (const float*)d_in[4];   // (256,) f32
    float*       out  = (float*)d_out;           // (20000,16) f32

    const int n_edges = in_sizes[1] / DIM;       // 640000
    const int n_atoms = in_sizes[0] / DIM;       // 20000

    // ws: counts[n_atoms*CSTR] | oflow_acc f32[n_atoms*DIM] | msgs bf16
    // (counts + oflow_acc contiguous -> ONE memset covers both)
    size_t counts_off = 0;
    size_t oacc_off   = counts_off + (size_t)n_atoms * CSTR * sizeof(int);
    size_t msgs_off   = oacc_off + (size_t)n_atoms * DIM * sizeof(float);
    size_t needed     = msgs_off + (size_t)n_atoms * CAP * DIM * sizeof(uint16_t);

    const int threads = 256;

    if (ws_size >= needed) {
        int*      counts    = (int*)((char*)d_ws + counts_off);
        float*    oflow_acc = (float*)((char*)d_ws + oacc_off);
        uint16_t* msgs      = (uint16_t*)((char*)d_ws + msgs_off);

        // zero counts + oflow_acc in one contiguous 2.56MB memset
        hipMemsetAsync(counts, 0, msgs_off, stream);

        const int n_groups = (n_edges + 15) / 16;
        const int waves    = (n_groups + GPW - 1) / GPW;
        const int mblocks  = (waves * 64 + threads - 1) / threads;
        msg_mfma_kernel<<<mblocks, threads, 0, stream>>>(
            atom, bond, pair, kern, bias, counts, oflow_acc, msgs,
            n_edges, n_groups);

        const int rthreads = n_atoms * 32;
        reduce_kernel<<<(rthreads + threads - 1) / threads, threads, 0, stream>>>(
            msgs, counts, oflow_acc, out, n_atoms);
    } else {
        hipMemsetAsync(out, 0, (size_t)out_size * sizeof(float), stream);
        edge_atomic_kernel<<<(n_edges + threads - 1) / threads, threads, 0, stream>>>(
            atom, bond, pair, kern, bias, out, n_edges);
    }
}